// Round 15
// baseline (576.983 us; speedup 1.0000x reference)
//
#include <hip/hip_runtime.h>

#define NB 256
#define NC_ 4
#define NT 4096
#define NPATCH 16
#define NP 256
#define NH 64
#define NK 128

typedef float f32x2 __attribute__((ext_vector_type(2)));
typedef float f32x4 __attribute__((ext_vector_type(4)));

// ws layout (floats)
#define OFF_TEMBM  0
#define OFF_TEMB0  64
#define OFF_MT     128
#define OFF_CC     8320
#define OFF_ZQSUM  8448
#define OFF_ZQ0    73984
#define OFF_COMMIT 139520
#define OFF_ADJ    140544
#define OFF_H0     144640

__device__ __forceinline__ float tanh_fast(float x) {
    float e = __expf(2.0f * x);
    return 1.0f - __fdividef(2.0f, e + 1.0f);
}
__device__ __forceinline__ float gelu_f(float x) {
    float x3 = x * x * x;
    float t = tanh_fast(0.7978845608028654f * (x + 0.044715f * x3));
    return 0.5f * x * (1.0f + t);
}
__device__ __forceinline__ float sigmoid_f(float x) {
    return __fdividef(1.0f, 1.0f + __expf(-x));
}

// ---------------- K0: precompute temb means, M = W_enc2 @ cb^T (PAIR-INTERLEAVED), cc
__global__ void k0_prep(const float* __restrict__ cb, const float* __restrict__ W_enc2,
                        const float* __restrict__ b_enc2, const float* __restrict__ W_time,
                        const float* __restrict__ b_time, float* __restrict__ ws) {
    const int t = threadIdx.x;
    if (blockIdx.x == 0) {
        __shared__ float ps[8][32], pc[8][32], sm[32], cm[32];
        const int k = t & 31, pg = t >> 5;
        const float step = 16.0f / 255.0f;
        const float lstep = (float)6.907755278982137 / 31.0f;
        const float fr = expf((float)k * lstep);
        float s_acc = 0.f, c_acc = 0.f;
        for (int pp = 0; pp < 32; ++pp) {
            int p = (pg << 5) + pp;
            float ang = ((float)p * step) * fr;
            s_acc += sinf(ang);
            c_acc += cosf(ang);
        }
        ps[pg][k] = s_acc; pc[pg][k] = c_acc;
        __syncthreads();
        if (t < 32) {
            float s = 0.f, c2 = 0.f;
            for (int g = 0; g < 8; ++g) { s += ps[g][t]; c2 += pc[g][t]; }
            sm[t] = s * (1.0f / 256.0f);
            cm[t] = c2 * (1.0f / 256.0f);
        }
        __syncthreads();
        if (t < 64) {
            float tm = b_time[t];
            float t0 = b_time[t];
            for (int kk = 0; kk < 32; ++kk) {
                tm = fmaf(sm[kk], W_time[kk * 64 + t], tm);
                tm = fmaf(cm[kk], W_time[(32 + kk) * 64 + t], tm);
                t0 += W_time[(32 + kk) * 64 + t];
            }
            ws[OFF_TEMBM + t] = tm;
            ws[OFF_TEMB0 + t] = t0;
        }
        if (t >= 128) {
            int j = t - 128;
            float cbn = 0.f, bc2 = 0.f;
            for (int hh = 0; hh < 64; ++hh) {
                float cv = cb[j * 64 + hh];
                cbn = fmaf(cv, cv, cbn);
                bc2 = fmaf(b_enc2[hh], cv, bc2);
            }
            ws[OFF_CC + j] = cbn - 2.0f * bc2;
        }
    } else {
        int oid = (blockIdx.x - 1) * 256 + t;   // 0..8191, = j*64+k
        int j = oid >> 6, kk = oid & 63;
        float acc = 0.f;
        for (int hh = 0; hh < 64; ++hh)
            acc = fmaf(W_enc2[kk * 64 + hh], cb[j * 64 + hh], acc);
        // pair-interleaved layout: [j/2][k][2]  (j,k) -> (j>>1)*128 + k*2 + (j&1)
        ws[OFF_MT + ((j >> 1) << 7) + (kk << 1) + (j & 1)] = acc;
    }
}

// ---------------- K1: encoder + VQ per (b,c), output-pair pk-FMA, scalar e1 --------
__global__ __launch_bounds__(256) void k1_encvq(
    const float* __restrict__ x, const float* __restrict__ cb,
    const float* __restrict__ W_enc, const float* __restrict__ b_enc,
    const float* __restrict__ W_enc2, const float* __restrict__ b_enc2,
    float* __restrict__ ws) {
    __shared__ float sW1[1024];    // W_enc as-is [k][h]
    __shared__ float sW2[4096];    // [k][h2]
    __shared__ float sMT[8192];    // pair-interleaved [j2][k][2]
    __shared__ float sCC[128];
    __shared__ float sB1[64];
    __shared__ float sB2[64];
    __shared__ int   sCnt[128];
    __shared__ float sScr[4];
    __shared__ int   sIdx0;

    const int t = threadIdx.x;
    const int bc = blockIdx.x;

    for (int i = t; i < 1024; i += 256) sW1[i] = W_enc[i];
    for (int i = t; i < 4096; i += 256) sW2[i] = W_enc2[i];
    for (int i = t; i < 8192; i += 256) sMT[i] = ws[OFF_MT + i];
    if (t < 128) { sCC[t] = ws[OFF_CC + t]; sCnt[t] = 0; }
    if (t < 64) sB1[t] = b_enc[t];
    else if (t < 128) sB2[t - 64] = b_enc2[t - 64];
    __syncthreads();

    const float4* xp = (const float4*)(x + (size_t)bc * NT + t * NPATCH);
    float4 xa = xp[0], xb = xp[1], xc = xp[2], xd = xp[3];
    float xx[16] = {xa.x,xa.y,xa.z,xa.w, xb.x,xb.y,xb.z,xb.w,
                    xc.x,xc.y,xc.z,xc.w, xd.x,xd.y,xd.z,xd.w};

    // stage 1: e1 = gelu(x @ W_enc + b_enc), output pairs packed, e1 stays scalar
    float e1[64];
    #pragma unroll
    for (int ch = 0; ch < 16; ++ch) {          // 4 outputs per chunk
        const int hb = ch << 2;
        f32x2 accA = {sB1[hb],     sB1[hb + 1]};
        f32x2 accB = {sB1[hb + 2], sB1[hb + 3]};
        #pragma unroll
        for (int kk = 0; kk < 16; ++kk) {
            f32x4 wv = *(const f32x4*)&sW1[(kk << 6) + hb];
            f32x2 xs = {xx[kk], xx[kk]};
            accA = __builtin_elementwise_fma(xs, __builtin_shufflevector(wv, wv, 0, 1), accA);
            accB = __builtin_elementwise_fma(xs, __builtin_shufflevector(wv, wv, 2, 3), accB);
        }
        e1[hb]     = gelu_f(accA.x);
        e1[hb + 1] = gelu_f(accA.y);
        e1[hb + 2] = gelu_f(accB.x);
        e1[hb + 3] = gelu_f(accB.y);
    }

    // stage 2: ze2 = ||e1 @ W_enc2 + b_enc2||^2 (chunked over h2, output pairs packed)
    float ze2 = 0.f;
    #pragma unroll 1
    for (int ch = 0; ch < 4; ++ch) {
        const int hb = ch << 4;
        f32x2 z2[8];
        #pragma unroll
        for (int i = 0; i < 8; ++i) z2[i] = f32x2{sB2[hb + 2 * i], sB2[hb + 2 * i + 1]};
        #pragma unroll
        for (int kk = 0; kk < 64; ++kk) {
            f32x2 es = {e1[kk], e1[kk]};
            const f32x4* w4 = (const f32x4*)(&sW2[(kk << 6) + hb]);
            f32x4 wa = w4[0], wb = w4[1], wc = w4[2], wd = w4[3];
            z2[0] = __builtin_elementwise_fma(es, __builtin_shufflevector(wa, wa, 0, 1), z2[0]);
            z2[1] = __builtin_elementwise_fma(es, __builtin_shufflevector(wa, wa, 2, 3), z2[1]);
            z2[2] = __builtin_elementwise_fma(es, __builtin_shufflevector(wb, wb, 0, 1), z2[2]);
            z2[3] = __builtin_elementwise_fma(es, __builtin_shufflevector(wb, wb, 2, 3), z2[3]);
            z2[4] = __builtin_elementwise_fma(es, __builtin_shufflevector(wc, wc, 0, 1), z2[4]);
            z2[5] = __builtin_elementwise_fma(es, __builtin_shufflevector(wc, wc, 2, 3), z2[5]);
            z2[6] = __builtin_elementwise_fma(es, __builtin_shufflevector(wd, wd, 0, 1), z2[6]);
            z2[7] = __builtin_elementwise_fma(es, __builtin_shufflevector(wd, wd, 2, 3), z2[7]);
        }
        f32x2 zs = {0.f, 0.f};
        #pragma unroll
        for (int i = 0; i < 8; ++i) zs = __builtin_elementwise_fma(z2[i], z2[i], zs);
        ze2 += zs.x + zs.y;
    }

    // VQ: argmin_j cc[j] - 2*e1.MT[j], codebook pairs packed (interleaved sMT)
    float bestscore = 3.4e38f; int best = 0;
    #pragma unroll 2
    for (int j2 = 0; j2 < 64; ++j2) {
        const f32x4* m4 = (const f32x4*)(&sMT[j2 << 7]);   // 32 float4 = 64 k's
        f32x2 dA = {0.f, 0.f}, dB = {0.f, 0.f}, dC = {0.f, 0.f}, dD = {0.f, 0.f};
        #pragma unroll
        for (int kk2 = 0; kk2 < 16; ++kk2) {
            f32x4 m = m4[kk2];
            dA = __builtin_elementwise_fma(f32x2{e1[2 * kk2], e1[2 * kk2]},
                                           __builtin_shufflevector(m, m, 0, 1), dA);
            dB = __builtin_elementwise_fma(f32x2{e1[2 * kk2 + 1], e1[2 * kk2 + 1]},
                                           __builtin_shufflevector(m, m, 2, 3), dB);
        }
        #pragma unroll
        for (int kk2 = 16; kk2 < 32; ++kk2) {
            f32x4 m = m4[kk2];
            dC = __builtin_elementwise_fma(f32x2{e1[2 * kk2], e1[2 * kk2]},
                                           __builtin_shufflevector(m, m, 0, 1), dC);
            dD = __builtin_elementwise_fma(f32x2{e1[2 * kk2 + 1], e1[2 * kk2 + 1]},
                                           __builtin_shufflevector(m, m, 2, 3), dD);
        }
        f32x2 dT = (dA + dB) + (dC + dD);
        float s0 = fmaf(-2.0f, dT.x, sCC[2 * j2]);
        float s1 = fmaf(-2.0f, dT.y, sCC[2 * j2 + 1]);
        if (s0 < bestscore) { bestscore = s0; best = 2 * j2; }
        if (s1 < bestscore) { bestscore = s1; best = 2 * j2 + 1; }
    }

    float cp = ze2 + bestscore;          // per-patch commit contribution
    #pragma unroll
    for (int off = 32; off; off >>= 1) cp += __shfl_xor(cp, off);
    if ((t & 63) == 0) sScr[t >> 6] = cp;
    atomicAdd(&sCnt[best], 1);
    if (t == 0) sIdx0 = best;
    __syncthreads();

    if (t < 64) {
        float acc = 0.f;
        for (int j = 0; j < 128; ++j)
            acc = fmaf((float)sCnt[j], cb[j * 64 + t], acc);
        ws[OFF_ZQSUM + bc * 64 + t] = acc;
    } else if (t < 128) {
        int hh = t - 64;
        ws[OFF_ZQ0 + bc * 64 + hh] = cb[sIdx0 * 64 + hh];
    } else if (t == 128) {
        ws[OFF_COMMIT + bc] = (sScr[0] + sScr[1]) + (sScr[2] + sScr[3]);
    }
}

// ---------------- K2: feat, h0, edge MLP, tau/focal/adjacency, losses ----------------
__global__ __launch_bounds__(256) void k2_graph(
    const float* __restrict__ W_lat, const float* __restrict__ b_lat,
    const float* __restrict__ W_e1, const float* __restrict__ b_e1,
    const float* __restrict__ W_e2, const float* __restrict__ b_e2,
    float* __restrict__ ws, float* __restrict__ out) {
    __shared__ float sWlat[4096];
    __shared__ float sWe1[8192];
    __shared__ float sWe2[128];
    __shared__ float sfeat[256];
    __shared__ float shid[1024];
    __shared__ float stau[16];
    __shared__ float scr2[4];

    const int t = threadIdx.x, b = blockIdx.x;
    const int c = t >> 6, h = t & 63;
    for (int i = t; i < 4096; i += 256) sWlat[i] = W_lat[i];
    for (int i = t; i < 8192; i += 256) sWe1[i] = W_e1[i];
    if (t < 128) sWe2[t] = W_e2[t];
    __syncthreads();

    const int bc = b * 4 + c;
    float zqm = ws[OFF_ZQSUM + bc * 64 + h] * (1.0f / 256.0f);
    float zq0 = ws[OFF_ZQ0 + bc * 64 + h];
    float base = b_lat[h];
    float ft = base + ws[OFF_TEMBM + h];
    float h0 = base + ws[OFF_TEMB0 + h];
    #pragma unroll
    for (int kk = 0; kk < 64; ++kk) {
        float w = sWlat[kk * 64 + h];
        ft = fmaf(__shfl(zqm, kk), w, ft);
        h0 = fmaf(__shfl(zq0, kk), w, h0);
    }
    ws[OFF_H0 + bc * 64 + h] = h0;
    sfeat[c * 64 + h] = ft;
    __syncthreads();

    #pragma unroll
    for (int pp = 0; pp < 4; ++pp) {
        const int p = pp * 4 + c;
        const int i = p >> 2, j = p & 3;
        float hv = b_e1[h];
        #pragma unroll
        for (int kk = 0; kk < 64; ++kk) {
            hv = fmaf(sfeat[i * 64 + kk], sWe1[kk * 64 + h], hv);
            hv = fmaf(sfeat[j * 64 + kk], sWe1[(64 + kk) * 64 + h], hv);
        }
        shid[p * 64 + h] = gelu_f(hv);
    }
    __syncthreads();

    if (t < 16) {
        const int p = t, i = p >> 2, j = p & 3;
        float e0 = 0.f, ev = 0.f;
        #pragma unroll
        for (int hh = 0; hh < 64; ++hh) {
            float g = shid[p * 64 + hh];
            e0 = fmaf(g, sWe2[hh * 2], e0);
            ev = fmaf(g, sWe2[hh * 2 + 1], ev);
        }
        e0 += b_e2[0]; ev += b_e2[1];
        float tv = sigmoid_f(ev);
        out[1536 + b * 16 + p] = tv;
        stau[p] = tv;
        ws[OFF_ADJ + b * 16 + p] = (i == j) ? 0.f : sigmoid_f(e0);
    }
    __syncthreads();
    if (t < 4) {
        out[512 + b * 4 + t] =
            -(((stau[t * 4] + stau[t * 4 + 1]) + stau[t * 4 + 2]) + stau[t * 4 + 3]);
    }
    if (b == 0) {
        float cp = (ws[OFF_COMMIT + t] + ws[OFF_COMMIT + 256 + t]) +
                   (ws[OFF_COMMIT + 512 + t] + ws[OFF_COMMIT + 768 + t]);
        #pragma unroll
        for (int off = 32; off; off >>= 1) cp += __shfl_xor(cp, off);
        if ((t & 63) == 0) scr2[t >> 6] = cp;
        __syncthreads();
        if (t == 0) {
            float m = ((scr2[0] + scr2[1]) + (scr2[2] + scr2[3])) * (1.0f / 16777216.0f);
            out[5632] = m; out[5633] = m;
        }
    }
}

// ---------------- K3: RK4 ODE scan (8 waves, k-half split, pk-FMA, tree-sum mix) ----
// Round-13/14 kernel exactly (measured best: 446-450us).
__global__ __launch_bounds__(512, 2) void k3_ode(
    const float* __restrict__ W_adj, const float* __restrict__ W_self, const float* __restrict__ b_ode,
    const float* __restrict__ ln_g, const float* __restrict__ ln_b,
    const float* __restrict__ W_h1, const float* __restrict__ b_h1,
    const float* __restrict__ W_h2, const float* __restrict__ b_h2,
    const float* __restrict__ ws, float* __restrict__ out) {
    __shared__ float sS[256];           // [c][k]; slice (c, 32j..32j+32) private to wave (c,j)
    __shared__ float sPU[2][4][64][2];  // [par][c][h][j]
    __shared__ float sPV[2][4][64][2];  // [par][c][h][j]

    const int t = threadIdx.x, b = blockIdx.x;
    const int w = t >> 6;
    const int q = w & 3;          // channel
    const int j = w >> 2;         // k-half
    const int h = t & 63;

    // this wave's 32 weight columns for lane h, as 16 k-pairs (64 VGPRs)
    f32x2 Wa2[16], Wsf2[16];
    #pragma unroll
    for (int i = 0; i < 16; ++i) {
        const int k0 = (j << 5) + (i << 1);
        Wa2[i]  = f32x2{W_adj[k0 * 64 + h],  W_adj[(k0 + 1) * 64 + h]};
        Wsf2[i] = f32x2{W_self[k0 * 64 + h], W_self[(k0 + 1) * 64 + h]};
    }

    const float* adjp = ws + OFF_ADJ + b * 16;
    const int c1 = (q + 1) & 3, c2 = (q + 2) & 3, c3 = (q + 3) & 3;
    const float A1 = adjp[q * 4 + c1];   // A[q][q] == 0 from K2 -> own pu never read
    const float A2 = adjp[q * 4 + c2];
    const float A3 = adjp[q * 4 + c3];
    const float bo = b_ode[h];

    float s = ws[OFF_H0 + (b * 4 + q) * 64 + h];
    float pool = s;
    const bool own = ((h >> 5) == j);
    if (own) sS[(q << 6) + h] = s;      // own slice; same-wave RAW only

    const float step = 16.0f / 255.0f;
    const int kb0 = (q << 6) + (j << 5);

    auto feval = [&](int par) __attribute__((always_inline)) -> float {
        f32x2 uA = {0.f, 0.f}, uB = {0.f, 0.f};
        f32x2 vA = {0.f, 0.f}, vB = {0.f, 0.f};
        #pragma unroll
        for (int i = 0; i < 8; ++i) {
            f32x4 sc = *(const f32x4*)&sS[kb0 + (i << 2)];
            f32x2 lo = __builtin_shufflevector(sc, sc, 0, 1);
            f32x2 hi = __builtin_shufflevector(sc, sc, 2, 3);
            uA = __builtin_elementwise_fma(lo, Wa2[2 * i],      uA);
            uB = __builtin_elementwise_fma(hi, Wa2[2 * i + 1],  uB);
            vA = __builtin_elementwise_fma(lo, Wsf2[2 * i],     vA);
            vB = __builtin_elementwise_fma(hi, Wsf2[2 * i + 1], vB);
        }
        f32x2 uT = uA + uB, vT = vA + vB;
        sPU[par][q][h][j] = uT.x + uT.y;
        sPV[par][q][h][j] = vT.x + vT.y;
        __syncthreads();            // the ONE barrier: all partials visible
        f32x2 p1 = *(const f32x2*)&sPU[par][c1][h][0];
        f32x2 p2 = *(const f32x2*)&sPU[par][c2][h][0];
        f32x2 p3 = *(const f32x2*)&sPU[par][c3][h][0];
        f32x2 pv = *(const f32x2*)&sPV[par][q][h][0];
        // tree-sum mix (shorter dependent chain than serial fmaf)
        float m01 = (pv.x + pv.y) + A1 * (p1.x + p1.y);
        float m23 = A2 * (p2.x + p2.y) + A3 * (p3.x + p3.y);
        return tanh_fast((m01 + m23) + bo);
    };

    #pragma unroll 1
    for (int it = 0; it < 255; ++it) {
        float dt = (float)(it + 1) * step - (float)it * step;
        float hdt = 0.5f * dt;
        float r1 = feval(0);
        if (own) sS[(q << 6) + h] = fmaf(hdt, r1, s);
        float r2 = feval(1);
        if (own) sS[(q << 6) + h] = fmaf(hdt, r2, s);
        float r3 = feval(0);
        if (own) sS[(q << 6) + h] = fmaf(dt, r3, s);
        float r4 = feval(1);
        s = fmaf(dt * (1.0f / 6.0f), ((r1 + r4) + 2.0f * (r2 + r3)), s);
        pool += s;
        if (own) sS[(q << 6) + h] = s;
    }

    // pool across channels
    __syncthreads();
    if (j == 0) sS[(q << 6) + h] = pool;
    __syncthreads();

    if (w == 0) {
        float pd = ((sS[h] + sS[64 + h]) + (sS[128 + h] + sS[192 + h])) * (1.0f / 1024.0f);
        float mu = pd;
        #pragma unroll
        for (int off = 32; off; off >>= 1) mu += __shfl_xor(mu, off);
        mu *= (1.0f / 64.0f);
        float dv = pd - mu;
        float vr = dv * dv;
        #pragma unroll
        for (int off = 32; off; off >>= 1) vr += __shfl_xor(vr, off);
        vr *= (1.0f / 64.0f);
        float nr = dv * rsqrtf(vr + 1e-5f) * ln_g[h] + ln_b[h];
        sS[h] = nr;   // wave-0 row, same-wave staging for broadcast reads
        float acc = b_h1[h];
        #pragma unroll
        for (int i = 0; i < 16; ++i) {
            f32x4 nv = *(const f32x4*)&sS[i << 2];
            acc = fmaf(nv.x, W_h1[(4 * i + 0) * 64 + h], acc);
            acc = fmaf(nv.y, W_h1[(4 * i + 1) * 64 + h], acc);
            acc = fmaf(nv.z, W_h1[(4 * i + 2) * 64 + h], acc);
            acc = fmaf(nv.w, W_h1[(4 * i + 3) * 64 + h], acc);
        }
        float g1 = gelu_f(acc);
        float l0 = g1 * W_h2[h * 2];
        float l1 = g1 * W_h2[h * 2 + 1];
        #pragma unroll
        for (int off = 32; off; off >>= 1) { l0 += __shfl_xor(l0, off); l1 += __shfl_xor(l1, off); }
        if (h == 0) {
            out[b * 2]     = l0 + b_h2[0];
            out[b * 2 + 1] = l1 + b_h2[1];
        }
    }
}

extern "C" void kernel_launch(void* const* d_in, const int* in_sizes, int n_in,
                              void* d_out, int out_size, void* d_ws, size_t ws_size,
                              hipStream_t stream) {
    (void)in_sizes; (void)n_in; (void)out_size; (void)ws_size;
    const float* x      = (const float*)d_in[0];
    const float* cb     = (const float*)d_in[1];
    const float* W_enc  = (const float*)d_in[2];
    const float* b_enc  = (const float*)d_in[3];
    const float* W_enc2 = (const float*)d_in[4];
    const float* b_enc2 = (const float*)d_in[5];
    const float* W_lat  = (const float*)d_in[6];
    const float* b_lat  = (const float*)d_in[7];
    const float* W_time = (const float*)d_in[8];
    const float* b_time = (const float*)d_in[9];
    const float* W_e1   = (const float*)d_in[10];
    const float* b_e1   = (const float*)d_in[11];
    const float* W_e2   = (const float*)d_in[12];
    const float* b_e2   = (const float*)d_in[13];
    const float* W_adj  = (const float*)d_in[14];
    const float* W_self = (const float*)d_in[15];
    const float* b_ode  = (const float*)d_in[16];
    const float* ln_g   = (const float*)d_in[17];
    const float* ln_b   = (const float*)d_in[18];
    const float* W_h1   = (const float*)d_in[19];
    const float* b_h1   = (const float*)d_in[20];
    const float* W_h2   = (const float*)d_in[21];
    const float* b_h2   = (const float*)d_in[22];
    float* out = (float*)d_out;
    float* ws  = (float*)d_ws;

    hipLaunchKernelGGL(k0_prep, dim3(33), dim3(256), 0, stream,
                       cb, W_enc2, b_enc2, W_time, b_time, ws);
    hipLaunchKernelGGL(k1_encvq, dim3(1024), dim3(256), 0, stream,
                       x, cb, W_enc, b_enc, W_enc2, b_enc2, ws);
    hipLaunchKernelGGL(k2_graph, dim3(256), dim3(256), 0, stream,
                       W_lat, b_lat, W_e1, b_e1, W_e2, b_e2, ws, out);
    hipLaunchKernelGGL(k3_ode, dim3(256), dim3(512), 0, stream,
                       W_adj, W_self, b_ode, ln_g, ln_b, W_h1, b_h1, W_h2, b_h2, ws, out);
}

// Round 16
// 566.673 us; speedup vs baseline: 1.0182x; 1.0182x over previous
//
#include <hip/hip_runtime.h>

#define NB 256
#define NC_ 4
#define NT 4096
#define NPATCH 16
#define NP 256
#define NH 64
#define NK 128

typedef float f32x2 __attribute__((ext_vector_type(2)));
typedef float f32x4 __attribute__((ext_vector_type(4)));

// ws layout (floats)
#define OFF_TEMBM  0
#define OFF_TEMB0  64
#define OFF_MT     128
#define OFF_CC     8320
#define OFF_ZQSUM  8448
#define OFF_ZQ0    73984
#define OFF_COMMIT 139520
#define OFF_ADJ    140544
#define OFF_H0     144640

__device__ __forceinline__ float tanh_fast(float x) {
    float e = __expf(2.0f * x);
    return 1.0f - __fdividef(2.0f, e + 1.0f);
}
__device__ __forceinline__ float gelu_f(float x) {
    float x3 = x * x * x;
    float t = tanh_fast(0.7978845608028654f * (x + 0.044715f * x3));
    return 0.5f * x * (1.0f + t);
}
__device__ __forceinline__ float sigmoid_f(float x) {
    return __fdividef(1.0f, 1.0f + __expf(-x));
}

// ---------------- K0: precompute temb means, M = W_enc2 @ cb^T, cc ----------------
__global__ void k0_prep(const float* __restrict__ cb, const float* __restrict__ W_enc2,
                        const float* __restrict__ b_enc2, const float* __restrict__ W_time,
                        const float* __restrict__ b_time, float* __restrict__ ws) {
    const int t = threadIdx.x;
    if (blockIdx.x == 0) {
        __shared__ float ps[8][32], pc[8][32], sm[32], cm[32];
        const int k = t & 31, pg = t >> 5;
        const float step = 16.0f / 255.0f;
        const float lstep = (float)6.907755278982137 / 31.0f;
        const float fr = expf((float)k * lstep);
        float s_acc = 0.f, c_acc = 0.f;
        for (int pp = 0; pp < 32; ++pp) {
            int p = (pg << 5) + pp;
            float ang = ((float)p * step) * fr;
            s_acc += sinf(ang);
            c_acc += cosf(ang);
        }
        ps[pg][k] = s_acc; pc[pg][k] = c_acc;
        __syncthreads();
        if (t < 32) {
            float s = 0.f, c2 = 0.f;
            for (int g = 0; g < 8; ++g) { s += ps[g][t]; c2 += pc[g][t]; }
            sm[t] = s * (1.0f / 256.0f);
            cm[t] = c2 * (1.0f / 256.0f);
        }
        __syncthreads();
        if (t < 64) {
            float tm = b_time[t];
            float t0 = b_time[t];
            for (int kk = 0; kk < 32; ++kk) {
                tm = fmaf(sm[kk], W_time[kk * 64 + t], tm);
                tm = fmaf(cm[kk], W_time[(32 + kk) * 64 + t], tm);
                t0 += W_time[(32 + kk) * 64 + t];
            }
            ws[OFF_TEMBM + t] = tm;
            ws[OFF_TEMB0 + t] = t0;
        }
        if (t >= 128) {
            int j = t - 128;
            float cbn = 0.f, bc2 = 0.f;
            for (int hh = 0; hh < 64; ++hh) {
                float cv = cb[j * 64 + hh];
                cbn = fmaf(cv, cv, cbn);
                bc2 = fmaf(b_enc2[hh], cv, bc2);
            }
            ws[OFF_CC + j] = cbn - 2.0f * bc2;
        }
    } else {
        int oid = (blockIdx.x - 1) * 256 + t;   // 0..8191, = j*64+k
        int j = oid >> 6, kk = oid & 63;
        float acc = 0.f;
        for (int hh = 0; hh < 64; ++hh)
            acc = fmaf(W_enc2[kk * 64 + hh], cb[j * 64 + hh], acc);
        ws[OFF_MT + oid] = acc;
    }
}

// ---------------- K1: encoder + VQ per (b,c), histogram z_q ----------------
__global__ __launch_bounds__(256) void k1_encvq(
    const float* __restrict__ x, const float* __restrict__ cb,
    const float* __restrict__ W_enc, const float* __restrict__ b_enc,
    const float* __restrict__ W_enc2, const float* __restrict__ b_enc2,
    float* __restrict__ ws) {
    __shared__ float sWeT[1024];   // [h][k] transposed W_enc
    __shared__ float sW2[4096];    // [k][h2]
    __shared__ float sMT[8192];    // [j][k]
    __shared__ float sCC[128];
    __shared__ float sB1[64];
    __shared__ float sB2[64];
    __shared__ int   sCnt[128];
    __shared__ float sScr[4];
    __shared__ int   sIdx0;

    const int t = threadIdx.x;
    const int bc = blockIdx.x;

    for (int i = t; i < 1024; i += 256) {
        int hh = i >> 4, kk = i & 15;
        sWeT[i] = W_enc[kk * 64 + hh];
    }
    for (int i = t; i < 4096; i += 256) sW2[i] = W_enc2[i];
    for (int i = t; i < 8192; i += 256) sMT[i] = ws[OFF_MT + i];
    if (t < 128) { sCC[t] = ws[OFF_CC + t]; sCnt[t] = 0; }
    if (t < 64) sB1[t] = b_enc[t];
    else if (t < 128) sB2[t - 64] = b_enc2[t - 64];
    __syncthreads();

    const float4* xp = (const float4*)(x + (size_t)bc * NT + t * NPATCH);
    float4 xa = xp[0], xb = xp[1], xc = xp[2], xd = xp[3];
    float xx[16] = {xa.x,xa.y,xa.z,xa.w, xb.x,xb.y,xb.z,xb.w,
                    xc.x,xc.y,xc.z,xc.w, xd.x,xd.y,xd.z,xd.w};

    // stage 1: e1 = gelu(x @ W_enc + b_enc)
    float e1[64];
    #pragma unroll
    for (int hh = 0; hh < 64; ++hh) {
        const float4* w4 = (const float4*)(&sWeT[hh * 16]);
        float4 wa = w4[0], wb = w4[1], wc = w4[2], wd = w4[3];
        float a = sB1[hh];
        a = fmaf(xx[0],  wa.x, a); a = fmaf(xx[1],  wa.y, a);
        a = fmaf(xx[2],  wa.z, a); a = fmaf(xx[3],  wa.w, a);
        a = fmaf(xx[4],  wb.x, a); a = fmaf(xx[5],  wb.y, a);
        a = fmaf(xx[6],  wb.z, a); a = fmaf(xx[7],  wb.w, a);
        a = fmaf(xx[8],  wc.x, a); a = fmaf(xx[9],  wc.y, a);
        a = fmaf(xx[10], wc.z, a); a = fmaf(xx[11], wc.w, a);
        a = fmaf(xx[12], wd.x, a); a = fmaf(xx[13], wd.y, a);
        a = fmaf(xx[14], wd.z, a); a = fmaf(xx[15], wd.w, a);
        e1[hh] = gelu_f(a);
    }

    // stage 2: ze2 = ||e1 @ W_enc2 + b_enc2||^2  (chunked over h2)
    float ze2 = 0.f;
    #pragma unroll 1
    for (int ch = 0; ch < 4; ++ch) {
        const int hb = ch << 4;
        float z[16];
        #pragma unroll
        for (int i = 0; i < 16; ++i) z[i] = sB2[hb + i];
        #pragma unroll
        for (int kk = 0; kk < 64; ++kk) {
            float ek = e1[kk];
            const float4* w4 = (const float4*)(&sW2[kk * 64 + hb]);
            float4 wa = w4[0], wb = w4[1], wc = w4[2], wd = w4[3];
            z[0]  = fmaf(ek, wa.x, z[0]);  z[1]  = fmaf(ek, wa.y, z[1]);
            z[2]  = fmaf(ek, wa.z, z[2]);  z[3]  = fmaf(ek, wa.w, z[3]);
            z[4]  = fmaf(ek, wb.x, z[4]);  z[5]  = fmaf(ek, wb.y, z[5]);
            z[6]  = fmaf(ek, wb.z, z[6]);  z[7]  = fmaf(ek, wb.w, z[7]);
            z[8]  = fmaf(ek, wc.x, z[8]);  z[9]  = fmaf(ek, wc.y, z[9]);
            z[10] = fmaf(ek, wc.z, z[10]); z[11] = fmaf(ek, wc.w, z[11]);
            z[12] = fmaf(ek, wd.x, z[12]); z[13] = fmaf(ek, wd.y, z[13]);
            z[14] = fmaf(ek, wd.z, z[14]); z[15] = fmaf(ek, wd.w, z[15]);
        }
        #pragma unroll
        for (int i = 0; i < 16; ++i) ze2 = fmaf(z[i], z[i], ze2);
    }

    // VQ: argmin_j  cc[j] - 2 * e1 . MT[j]
    float bestscore = 3.4e38f; int best = 0;
    #pragma unroll 2
    for (int j = 0; j < 128; ++j) {
        const float4* m4 = (const float4*)(&sMT[j * 64]);
        float d0 = 0.f, d1 = 0.f, d2 = 0.f, d3 = 0.f;
        #pragma unroll
        for (int kk = 0; kk < 16; ++kk) {
            float4 m = m4[kk];
            d0 = fmaf(e1[4 * kk],     m.x, d0);
            d1 = fmaf(e1[4 * kk + 1], m.y, d1);
            d2 = fmaf(e1[4 * kk + 2], m.z, d2);
            d3 = fmaf(e1[4 * kk + 3], m.w, d3);
        }
        float score = fmaf(-2.0f, (d0 + d1) + (d2 + d3), sCC[j]);
        if (score < bestscore) { bestscore = score; best = j; }
    }

    float cp = ze2 + bestscore;          // per-patch commit contribution
    #pragma unroll
    for (int off = 32; off; off >>= 1) cp += __shfl_xor(cp, off);
    if ((t & 63) == 0) sScr[t >> 6] = cp;
    atomicAdd(&sCnt[best], 1);
    if (t == 0) sIdx0 = best;
    __syncthreads();

    if (t < 64) {
        float acc = 0.f;
        for (int j = 0; j < 128; ++j)
            acc = fmaf((float)sCnt[j], cb[j * 64 + t], acc);
        ws[OFF_ZQSUM + bc * 64 + t] = acc;
    } else if (t < 128) {
        int hh = t - 64;
        ws[OFF_ZQ0 + bc * 64 + hh] = cb[sIdx0 * 64 + hh];
    } else if (t == 128) {
        ws[OFF_COMMIT + bc] = (sScr[0] + sScr[1]) + (sScr[2] + sScr[3]);
    }
}

// ---------------- K2: feat, h0, edge MLP, tau/focal/adjacency, losses ----------------
__global__ __launch_bounds__(256) void k2_graph(
    const float* __restrict__ W_lat, const float* __restrict__ b_lat,
    const float* __restrict__ W_e1, const float* __restrict__ b_e1,
    const float* __restrict__ W_e2, const float* __restrict__ b_e2,
    float* __restrict__ ws, float* __restrict__ out) {
    __shared__ float sWlat[4096];
    __shared__ float sWe1[8192];
    __shared__ float sWe2[128];
    __shared__ float sfeat[256];
    __shared__ float shid[1024];
    __shared__ float stau[16];
    __shared__ float scr2[4];

    const int t = threadIdx.x, b = blockIdx.x;
    const int c = t >> 6, h = t & 63;
    for (int i = t; i < 4096; i += 256) sWlat[i] = W_lat[i];
    for (int i = t; i < 8192; i += 256) sWe1[i] = W_e1[i];
    if (t < 128) sWe2[t] = W_e2[t];
    __syncthreads();

    const int bc = b * 4 + c;
    float zqm = ws[OFF_ZQSUM + bc * 64 + h] * (1.0f / 256.0f);
    float zq0 = ws[OFF_ZQ0 + bc * 64 + h];
    float base = b_lat[h];
    float ft = base + ws[OFF_TEMBM + h];
    float h0 = base + ws[OFF_TEMB0 + h];
    #pragma unroll
    for (int kk = 0; kk < 64; ++kk) {
        float w = sWlat[kk * 64 + h];
        ft = fmaf(__shfl(zqm, kk), w, ft);
        h0 = fmaf(__shfl(zq0, kk), w, h0);
    }
    ws[OFF_H0 + bc * 64 + h] = h0;
    sfeat[c * 64 + h] = ft;
    __syncthreads();

    #pragma unroll
    for (int pp = 0; pp < 4; ++pp) {
        const int p = pp * 4 + c;
        const int i = p >> 2, j = p & 3;
        float hv = b_e1[h];
        #pragma unroll
        for (int kk = 0; kk < 64; ++kk) {
            hv = fmaf(sfeat[i * 64 + kk], sWe1[kk * 64 + h], hv);
            hv = fmaf(sfeat[j * 64 + kk], sWe1[(64 + kk) * 64 + h], hv);
        }
        shid[p * 64 + h] = gelu_f(hv);
    }
    __syncthreads();

    if (t < 16) {
        const int p = t, i = p >> 2, j = p & 3;
        float e0 = 0.f, ev = 0.f;
        #pragma unroll
        for (int hh = 0; hh < 64; ++hh) {
            float g = shid[p * 64 + hh];
            e0 = fmaf(g, sWe2[hh * 2], e0);
            ev = fmaf(g, sWe2[hh * 2 + 1], ev);
        }
        e0 += b_e2[0]; ev += b_e2[1];
        float tv = sigmoid_f(ev);
        out[1536 + b * 16 + p] = tv;
        stau[p] = tv;
        ws[OFF_ADJ + b * 16 + p] = (i == j) ? 0.f : sigmoid_f(e0);
    }
    __syncthreads();
    if (t < 4) {
        out[512 + b * 4 + t] =
            -(((stau[t * 4] + stau[t * 4 + 1]) + stau[t * 4 + 2]) + stau[t * 4 + 3]);
    }
    if (b == 0) {
        float cp = (ws[OFF_COMMIT + t] + ws[OFF_COMMIT + 256 + t]) +
                   (ws[OFF_COMMIT + 512 + t] + ws[OFF_COMMIT + 768 + t]);
        #pragma unroll
        for (int off = 32; off; off >>= 1) cp += __shfl_xor(cp, off);
        if ((t & 63) == 0) scr2[t >> 6] = cp;
        __syncthreads();
        if (t == 0) {
            float m = ((scr2[0] + scr2[1]) + (scr2[2] + scr2[3])) * (1.0f / 16777216.0f);
            out[5632] = m; out[5633] = m;
        }
    }
}

// ---------------- K3: RK4 ODE scan (8 waves, k-half split, pk-FMA, tree-sum mix) ----
// Round-13/14 kernel exactly (measured best: 446-450us).
__global__ __launch_bounds__(512, 2) void k3_ode(
    const float* __restrict__ W_adj, const float* __restrict__ W_self, const float* __restrict__ b_ode,
    const float* __restrict__ ln_g, const float* __restrict__ ln_b,
    const float* __restrict__ W_h1, const float* __restrict__ b_h1,
    const float* __restrict__ W_h2, const float* __restrict__ b_h2,
    const float* __restrict__ ws, float* __restrict__ out) {
    __shared__ float sS[256];           // [c][k]; slice (c, 32j..32j+32) private to wave (c,j)
    __shared__ float sPU[2][4][64][2];  // [par][c][h][j]
    __shared__ float sPV[2][4][64][2];  // [par][c][h][j]

    const int t = threadIdx.x, b = blockIdx.x;
    const int w = t >> 6;
    const int q = w & 3;          // channel
    const int j = w >> 2;         // k-half
    const int h = t & 63;

    // this wave's 32 weight columns for lane h, as 16 k-pairs (64 VGPRs)
    f32x2 Wa2[16], Wsf2[16];
    #pragma unroll
    for (int i = 0; i < 16; ++i) {
        const int k0 = (j << 5) + (i << 1);
        Wa2[i]  = f32x2{W_adj[k0 * 64 + h],  W_adj[(k0 + 1) * 64 + h]};
        Wsf2[i] = f32x2{W_self[k0 * 64 + h], W_self[(k0 + 1) * 64 + h]};
    }

    const float* adjp = ws + OFF_ADJ + b * 16;
    const int c1 = (q + 1) & 3, c2 = (q + 2) & 3, c3 = (q + 3) & 3;
    const float A1 = adjp[q * 4 + c1];   // A[q][q] == 0 from K2 -> own pu never read
    const float A2 = adjp[q * 4 + c2];
    const float A3 = adjp[q * 4 + c3];
    const float bo = b_ode[h];

    float s = ws[OFF_H0 + (b * 4 + q) * 64 + h];
    float pool = s;
    const bool own = ((h >> 5) == j);
    if (own) sS[(q << 6) + h] = s;      // own slice; same-wave RAW only

    const float step = 16.0f / 255.0f;
    const int kb0 = (q << 6) + (j << 5);

    auto feval = [&](int par) __attribute__((always_inline)) -> float {
        f32x2 uA = {0.f, 0.f}, uB = {0.f, 0.f};
        f32x2 vA = {0.f, 0.f}, vB = {0.f, 0.f};
        #pragma unroll
        for (int i = 0; i < 8; ++i) {
            f32x4 sc = *(const f32x4*)&sS[kb0 + (i << 2)];
            f32x2 lo = __builtin_shufflevector(sc, sc, 0, 1);
            f32x2 hi = __builtin_shufflevector(sc, sc, 2, 3);
            uA = __builtin_elementwise_fma(lo, Wa2[2 * i],      uA);
            uB = __builtin_elementwise_fma(hi, Wa2[2 * i + 1],  uB);
            vA = __builtin_elementwise_fma(lo, Wsf2[2 * i],     vA);
            vB = __builtin_elementwise_fma(hi, Wsf2[2 * i + 1], vB);
        }
        f32x2 uT = uA + uB, vT = vA + vB;
        sPU[par][q][h][j] = uT.x + uT.y;
        sPV[par][q][h][j] = vT.x + vT.y;
        __syncthreads();            // the ONE barrier: all partials visible
        f32x2 p1 = *(const f32x2*)&sPU[par][c1][h][0];
        f32x2 p2 = *(const f32x2*)&sPU[par][c2][h][0];
        f32x2 p3 = *(const f32x2*)&sPU[par][c3][h][0];
        f32x2 pv = *(const f32x2*)&sPV[par][q][h][0];
        // tree-sum mix (shorter dependent chain than serial fmaf)
        float m01 = (pv.x + pv.y) + A1 * (p1.x + p1.y);
        float m23 = A2 * (p2.x + p2.y) + A3 * (p3.x + p3.y);
        return tanh_fast((m01 + m23) + bo);
    };

    #pragma unroll 1
    for (int it = 0; it < 255; ++it) {
        float dt = (float)(it + 1) * step - (float)it * step;
        float hdt = 0.5f * dt;
        float r1 = feval(0);
        if (own) sS[(q << 6) + h] = fmaf(hdt, r1, s);
        float r2 = feval(1);
        if (own) sS[(q << 6) + h] = fmaf(hdt, r2, s);
        float r3 = feval(0);
        if (own) sS[(q << 6) + h] = fmaf(dt, r3, s);
        float r4 = feval(1);
        s = fmaf(dt * (1.0f / 6.0f), ((r1 + r4) + 2.0f * (r2 + r3)), s);
        pool += s;
        if (own) sS[(q << 6) + h] = s;
    }

    // pool across channels
    __syncthreads();
    if (j == 0) sS[(q << 6) + h] = pool;
    __syncthreads();

    if (w == 0) {
        float pd = ((sS[h] + sS[64 + h]) + (sS[128 + h] + sS[192 + h])) * (1.0f / 1024.0f);
        float mu = pd;
        #pragma unroll
        for (int off = 32; off; off >>= 1) mu += __shfl_xor(mu, off);
        mu *= (1.0f / 64.0f);
        float dv = pd - mu;
        float vr = dv * dv;
        #pragma unroll
        for (int off = 32; off; off >>= 1) vr += __shfl_xor(vr, off);
        vr *= (1.0f / 64.0f);
        float nr = dv * rsqrtf(vr + 1e-5f) * ln_g[h] + ln_b[h];
        sS[h] = nr;   // wave-0 row, same-wave staging for broadcast reads
        float acc = b_h1[h];
        #pragma unroll
        for (int i = 0; i < 16; ++i) {
            f32x4 nv = *(const f32x4*)&sS[i << 2];
            acc = fmaf(nv.x, W_h1[(4 * i + 0) * 64 + h], acc);
            acc = fmaf(nv.y, W_h1[(4 * i + 1) * 64 + h], acc);
            acc = fmaf(nv.z, W_h1[(4 * i + 2) * 64 + h], acc);
            acc = fmaf(nv.w, W_h1[(4 * i + 3) * 64 + h], acc);
        }
        float g1 = gelu_f(acc);
        float l0 = g1 * W_h2[h * 2];
        float l1 = g1 * W_h2[h * 2 + 1];
        #pragma unroll
        for (int off = 32; off; off >>= 1) { l0 += __shfl_xor(l0, off); l1 += __shfl_xor(l1, off); }
        if (h == 0) {
            out[b * 2]     = l0 + b_h2[0];
            out[b * 2 + 1] = l1 + b_h2[1];
        }
    }
}

extern "C" void kernel_launch(void* const* d_in, const int* in_sizes, int n_in,
                              void* d_out, int out_size, void* d_ws, size_t ws_size,
                              hipStream_t stream) {
    (void)in_sizes; (void)n_in; (void)out_size; (void)ws_size;
    const float* x      = (const float*)d_in[0];
    const float* cb     = (const float*)d_in[1];
    const float* W_enc  = (const float*)d_in[2];
    const float* b_enc  = (const float*)d_in[3];
    const float* W_enc2 = (const float*)d_in[4];
    const float* b_enc2 = (const float*)d_in[5];
    const float* W_lat  = (const float*)d_in[6];
    const float* b_lat  = (const float*)d_in[7];
    const float* W_time = (const float*)d_in[8];
    const float* b_time = (const float*)d_in[9];
    const float* W_e1   = (const float*)d_in[10];
    const float* b_e1   = (const float*)d_in[11];
    const float* W_e2   = (const float*)d_in[12];
    const float* b_e2   = (const float*)d_in[13];
    const float* W_adj  = (const float*)d_in[14];
    const float* W_self = (const float*)d_in[15];
    const float* b_ode  = (const float*)d_in[16];
    const float* ln_g   = (const float*)d_in[17];
    const float* ln_b   = (const float*)d_in[18];
    const float* W_h1   = (const float*)d_in[19];
    const float* b_h1   = (const float*)d_in[20];
    const float* W_h2   = (const float*)d_in[21];
    const float* b_h2   = (const float*)d_in[22];
    float* out = (float*)d_out;
    float* ws  = (float*)d_ws;

    hipLaunchKernelGGL(k0_prep, dim3(33), dim3(256), 0, stream,
                       cb, W_enc2, b_enc2, W_time, b_time, ws);
    hipLaunchKernelGGL(k1_encvq, dim3(1024), dim3(256), 0, stream,
                       x, cb, W_enc, b_enc, W_enc2, b_enc2, ws);
    hipLaunchKernelGGL(k2_graph, dim3(256), dim3(256), 0, stream,
                       W_lat, b_lat, W_e1, b_e1, W_e2, b_e2, ws, out);
    hipLaunchKernelGGL(k3_ode, dim3(256), dim3(512), 0, stream,
                       W_adj, W_self, b_ode, ln_g, ln_b, W_h1, b_h1, W_h2, b_h2, ws, out);
}